// Round 1
// baseline (86.207 us; speedup 1.0000x reference)
//
#include <hip/hip_runtime.h>

#define IN_F  8192
#define OUT_F 8192
#define BATCH 16
#define KSTEP 256
#define NSTEPS (IN_F / KSTEP)   // 32
#define ROWS_PER_BLOCK 16       // 4 waves x 4 rows
#define THREADS 256

__global__ __launch_bounds__(THREADS, 2)
void gptq_linear_kernel(const float* __restrict__ x,
                        const int*  __restrict__ qw,
                        const float* __restrict__ scale,
                        const float* __restrict__ bias,
                        float* __restrict__ out)
{
    __shared__ float xs[2][BATCH][KSTEP];   // 32 KB double-buffered x tile

    const int tid  = threadIdx.x;
    const int lane = tid & 63;
    const int wave = tid >> 6;
    const int row0 = blockIdx.x * ROWS_PER_BLOCK + wave * 4;
    const int kl   = lane * 4;              // lane's k offset within a step (4 floats)

    // ---- prologue: load x tile 0 + w tile 0 ----
    float4 xstage[4];
    #pragma unroll
    for (int j = 0; j < 4; ++j) {
        const int b = wave * 4 + j;
        xstage[j] = *reinterpret_cast<const float4*>(x + (size_t)b * IN_F + kl);
    }
    int4 wcur[4];
    #pragma unroll
    for (int r = 0; r < 4; ++r)
        wcur[r] = *reinterpret_cast<const int4*>(qw + (size_t)(row0 + r) * IN_F + kl);
    #pragma unroll
    for (int j = 0; j < 4; ++j) {
        const int b = wave * 4 + j;
        *reinterpret_cast<float4*>(&xs[0][b][kl]) = xstage[j];
    }
    __syncthreads();

    float acc[64];
    #pragma unroll
    for (int i = 0; i < 64; ++i) acc[i] = 0.0f;

    for (int step = 0; step < NSTEPS; ++step) {
        const int buf = step & 1;
        const int ktn = (step + 1) * KSTEP;
        const bool has_next = (step + 1 < NSTEPS);

        // issue next-step loads early (latency hides under compute below)
        int4 wnext[4];
        if (has_next) {
            #pragma unroll
            for (int j = 0; j < 4; ++j) {
                const int b = wave * 4 + j;
                xstage[j] = *reinterpret_cast<const float4*>(x + (size_t)b * IN_F + ktn + kl);
            }
            #pragma unroll
            for (int r = 0; r < 4; ++r)
                wnext[r] = *reinterpret_cast<const int4*>(qw + (size_t)(row0 + r) * IN_F + ktn + kl);
        }

        // convert current weights (int4 values, exact in fp32)
        float wf[4][4];
        #pragma unroll
        for (int r = 0; r < 4; ++r) {
            wf[r][0] = (float)wcur[r].x;
            wf[r][1] = (float)wcur[r].y;
            wf[r][2] = (float)wcur[r].z;
            wf[r][3] = (float)wcur[r].w;
        }

        // main compute: 16 ds_read_b128 + 256 v_fmac per thread
        #pragma unroll
        for (int b = 0; b < BATCH; ++b) {
            const float4 xb = *reinterpret_cast<const float4*>(&xs[buf][b][kl]);
            #pragma unroll
            for (int r = 0; r < 4; ++r) {
                acc[r*16 + b] += wf[r][0] * xb.x;
                acc[r*16 + b] += wf[r][1] * xb.y;
                acc[r*16 + b] += wf[r][2] * xb.z;
                acc[r*16 + b] += wf[r][3] * xb.w;
            }
        }

        // write next x tile late (loads have drained by now), then barrier
        if (has_next) {
            #pragma unroll
            for (int j = 0; j < 4; ++j) {
                const int b = wave * 4 + j;
                *reinterpret_cast<float4*>(&xs[buf ^ 1][b][kl]) = xstage[j];
            }
            #pragma unroll
            for (int r = 0; r < 4; ++r) wcur[r] = wnext[r];
        }
        __syncthreads();
    }

    // ---- recursive-halving reduction across the 64-lane k-split ----
    // After 6 levels, lane l holds the full 64-lane sum of acc[bitrev6(l)].
    #pragma unroll
    for (int m = 1, half = 32; m <= 32; m <<= 1, half >>= 1) {
        const bool hi = (lane & m) != 0;
        #pragma unroll
        for (int i = 0; i < half; ++i) {
            const float send = hi ? acc[i] : acc[half + i];
            const float recv = __shfl_xor(send, m, 64);
            const float keep = hi ? acc[half + i] : acc[i];
            acc[i] = keep + recv;
        }
    }

    const int idx = ((lane & 1)  << 5) | ((lane & 2)  << 3) | ((lane & 4)  << 1)
                  | ((lane & 8)  >> 1) | ((lane & 16) >> 3) | ((lane & 32) >> 5);
    const int r = idx >> 4;        // 0..3  (row within wave's 4)
    const int b = idx & 15;        // 0..15 (batch)
    const int o = row0 + r;

    const float s = scale[0];
    out[(size_t)b * OUT_F + o] = acc[0] * s + bias[o];
}

extern "C" void kernel_launch(void* const* d_in, const int* in_sizes, int n_in,
                              void* d_out, int out_size, void* d_ws, size_t ws_size,
                              hipStream_t stream) {
    const float* x     = (const float*)d_in[0];
    const int*   qw    = (const int*)d_in[1];
    const float* scale = (const float*)d_in[2];
    const float* bias  = (const float*)d_in[3];
    float*       out   = (float*)d_out;

    dim3 grid(OUT_F / ROWS_PER_BLOCK);   // 512 blocks
    gptq_linear_kernel<<<grid, THREADS, 0, stream>>>(x, qw, scale, bias, out);
}

// Round 2
// 67.553 us; speedup vs baseline: 1.2761x; 1.2761x over previous
//
#include <hip/hip_runtime.h>

#define IN_F  8192
#define OUT_F 8192
#define BATCH 16
#define KSPLIT 8
#define KCHUNK (IN_F / KSPLIT)   // 1024 k per block
#define KSTEP  128
#define NSTEPS (KCHUNK / KSTEP)  // 8
#define ROWS_PER_BLOCK 16        // 4 waves x 4 rows
#define THREADS 256

// out[b][o] = bias[o]  (also zero-initializes for the atomic accumulation)
__global__ __launch_bounds__(256)
void init_out_kernel(const float* __restrict__ bias, float* __restrict__ out)
{
    const int i = blockIdx.x * 256 + threadIdx.x;     // 0 .. BATCH*OUT_F-1
    out[i] = bias[i & (OUT_F - 1)];
}

__global__ __launch_bounds__(THREADS, 4)
void gptq_main_kernel(const float* __restrict__ x,
                      const int*  __restrict__ qw,
                      const float* __restrict__ scale,
                      float* __restrict__ out)
{
    __shared__ float xs[2][BATCH * KSTEP];   // 2 x 8 KB, double-buffered x tile

    const int tid  = threadIdx.x;
    const int lane = tid & 63;
    const int wave = tid >> 6;
    const int row0 = blockIdx.x * ROWS_PER_BLOCK + wave * 4;
    const int kbase = blockIdx.y * KCHUNK;

    // flat-contiguous x staging: thread t writes tile floats [4t..4t+3] and [1024+4t..]
    const int i1 = tid * 4;
    const int i2 = BATCH * KSTEP / 2 + tid * 4;
    const int b1 = i1 >> 7, k1 = i1 & (KSTEP - 1);
    const int b2 = i2 >> 7, k2 = i2 & (KSTEP - 1);

    // ---- prologue: stage step 0 ----
    float4 nx0 = *reinterpret_cast<const float4*>(x + (size_t)b1 * IN_F + kbase + k1);
    float4 nx1 = *reinterpret_cast<const float4*>(x + (size_t)b2 * IN_F + kbase + k2);
    int2 wcur[4];
    #pragma unroll
    for (int r = 0; r < 4; ++r)
        wcur[r] = *reinterpret_cast<const int2*>(qw + (size_t)(row0 + r) * IN_F + kbase + lane * 2);
    *reinterpret_cast<float4*>(&xs[0][i1]) = nx0;
    *reinterpret_cast<float4*>(&xs[0][i2]) = nx1;
    __syncthreads();

    float acc[64];
    #pragma unroll
    for (int i = 0; i < 64; ++i) acc[i] = 0.0f;

    #pragma unroll
    for (int step = 0; step < NSTEPS; ++step) {
        const int buf = step & 1;
        const bool has_next = (step + 1 < NSTEPS);

        // issue next-step loads early; latency hides under the FMAs below
        int2 wnext[4];
        if (has_next) {
            const int kg = kbase + (step + 1) * KSTEP;
            nx0 = *reinterpret_cast<const float4*>(x + (size_t)b1 * IN_F + kg + k1);
            nx1 = *reinterpret_cast<const float4*>(x + (size_t)b2 * IN_F + kg + k2);
            #pragma unroll
            for (int r = 0; r < 4; ++r)
                wnext[r] = *reinterpret_cast<const int2*>(qw + (size_t)(row0 + r) * IN_F + kg + lane * 2);
        }

        // int4 weights are exact in fp32
        float wf[4][2];
        #pragma unroll
        for (int r = 0; r < 4; ++r) {
            wf[r][0] = (float)wcur[r].x;
            wf[r][1] = (float)wcur[r].y;
        }

        // 16 ds_read_b64 + 128 v_fmac per thread per step
        #pragma unroll
        for (int b = 0; b < BATCH; ++b) {
            const float2 xv = *reinterpret_cast<const float2*>(&xs[buf][b * KSTEP + lane * 2]);
            #pragma unroll
            for (int r = 0; r < 4; ++r) {
                acc[r * 16 + b] += wf[r][0] * xv.x;
                acc[r * 16 + b] += wf[r][1] * xv.y;
            }
        }

        // write next tile late, then barrier
        if (has_next) {
            *reinterpret_cast<float4*>(&xs[buf ^ 1][i1]) = nx0;
            *reinterpret_cast<float4*>(&xs[buf ^ 1][i2]) = nx1;
            #pragma unroll
            for (int r = 0; r < 4; ++r) wcur[r] = wnext[r];
        }
        __syncthreads();
    }

    // ---- recursive-halving reduction across the 64-lane k-split ----
    #pragma unroll
    for (int m = 1, half = 32; m <= 32; m <<= 1, half >>= 1) {
        const bool hi = (lane & m) != 0;
        #pragma unroll
        for (int i = 0; i < half; ++i) {
            const float send = hi ? acc[i] : acc[half + i];
            const float recv = __shfl_xor(send, m, 64);
            const float keep = hi ? acc[half + i] : acc[i];
            acc[i] = keep + recv;
        }
    }

    const int idx = ((lane & 1)  << 5) | ((lane & 2)  << 3) | ((lane & 4)  << 1)
                  | ((lane & 8)  >> 1) | ((lane & 16) >> 3) | ((lane & 32) >> 5);
    const int r = idx >> 4;        // row within wave's 4
    const int b = idx & 15;        // batch
    const int o = row0 + r;

    atomicAdd(out + (size_t)b * OUT_F + o, acc[0] * scale[0]);
}

extern "C" void kernel_launch(void* const* d_in, const int* in_sizes, int n_in,
                              void* d_out, int out_size, void* d_ws, size_t ws_size,
                              hipStream_t stream) {
    const float* x     = (const float*)d_in[0];
    const int*   qw    = (const int*)d_in[1];
    const float* scale = (const float*)d_in[2];
    const float* bias  = (const float*)d_in[3];
    float*       out   = (float*)d_out;

    init_out_kernel<<<(BATCH * OUT_F) / 256, 256, 0, stream>>>(bias, out);

    dim3 grid(OUT_F / ROWS_PER_BLOCK, KSPLIT);   // 512 x 8 = 4096 blocks
    gptq_main_kernel<<<grid, THREADS, 0, stream>>>(x, qw, scale, out);
}